// Round 17
// baseline (166.963 us; speedup 1.0000x reference)
//
#include <hip/hip_runtime.h>
#include <hip/hip_fp16.h>

constexpr int N = 50000;        // nodes
constexpr int D = 64;           // feature dim
constexpr int E = 1600000;      // edges
constexpr int NBUCK = (N + 127) / 128;   // 391 buckets of 128 nodes (dst>>7)
constexpr int CAP = 4608;                // bucket window capacity (mean 4092)
constexpr int BTHREADS = 512;
constexpr int BBLOCKS = 512;             // 2 blocks/CU exactly
constexpr int EPB = E / BBLOCKS;         // 3125 edges per block (exact)
constexpr int CPT = (EPB + BTHREADS - 1) / BTHREADS;  // 7

// ---------------------------------------------------------------------------
// K1: privatized counting-sort scatter -> fixed-capacity bucket windows.
// packed = dst<<16 | src (both < 65536); bucket = packed>>23.
// cursor[] holds per-bucket COUNTS (zeroed by memset); chunk base is
// b*CAP + old_count. Edges permuted into bucket-sorted order in LDS first
// (contiguous chunk writes); hierarchical wave-shfl scan.
__global__ void k_bucket(const int* __restrict__ src, const int* __restrict__ dst,
                         int* __restrict__ cursor, unsigned* __restrict__ packed) {
    __shared__ int lh[NBUCK];
    __shared__ int scanI[NBUCK];         // inclusive prefix over buckets
    __shared__ int wsum[8];
    __shared__ int lb[NBUCK];
    __shared__ unsigned stage[EPB];      // 12.5 KB
    int tid = threadIdx.x;
    if (tid < NBUCK) lh[tid] = 0;
    __syncthreads();
    int base_e = blockIdx.x * EPB;
    unsigned pk[CPT];
    int bn[CPT], rk[CPT];
#pragma unroll
    for (int i = 0; i < CPT; ++i) {
        int idx = i * BTHREADS + tid;
        if (idx < EPB) {
            int e = base_e + idx;
            int d = dst[e];
            int s = src[e];
            bn[i] = d >> 7;
            pk[i] = ((unsigned)d << 16) | (unsigned)s;
            rk[i] = atomicAdd(&lh[bn[i]], 1);
        } else bn[i] = -1;
    }
    __syncthreads();
    // hierarchical inclusive scan of lh[0..NBUCK) into scanI
    int w = tid >> 6, l = tid & 63;
    int v = (tid < NBUCK) ? lh[tid] : 0;
    for (int off = 1; off < 64; off <<= 1) {
        int t = __shfl_up(v, off, 64);
        if (l >= off) v += t;
    }
    if (tid < NBUCK) scanI[tid] = v;
    if (l == 63) wsum[w] = v;
    __syncthreads();
    if (tid < 64) {                      // wave 0 scans the 8 wave sums
        int s = (tid < 8) ? wsum[tid] : 0;
        for (int off = 1; off < 8; off <<= 1) {
            int t = __shfl_up(s, off, 64);
            if (tid >= off) s += t;
        }
        if (tid < 8) wsum[tid] = s;
    }
    __syncthreads();
    if (tid < NBUCK && w > 0) scanI[tid] += wsum[w - 1];
    if (tid < NBUCK) {
        int c = lh[tid];
        lb[tid] = tid * CAP + (c ? atomicAdd(&cursor[tid], c) : 0);
    }
    __syncthreads();
#pragma unroll
    for (int i = 0; i < CPT; ++i) {
        if (bn[i] >= 0) {
            int eb = (bn[i] == 0) ? 0 : scanI[bn[i] - 1];
            stage[eb + rk[i]] = pk[i];   // LDS scatter into bucket-sorted order
        }
    }
    __syncthreads();
    for (int j = tid; j < EPB; j += BTHREADS) {
        unsigned vv = stage[j];
        int bk = vv >> 23;               // dst>>7
        int eb = (bk == 0) ? 0 : scanI[bk - 1];
        packed[lb[bk] + (j - eb)] = vv;  // contiguous within each chunk
    }
}

// K2: one block (1024 thr) per 128-node bucket — LDS hist + single-wave shfl
// scan -> rowptr/rowend/norm; fill node-sorted u16 src into LDS stage, then
// coalesced uint copy-out to the bucket's CSR window.
__global__ void k_csr(const int* __restrict__ cursor, const unsigned* __restrict__ packed,
                      unsigned short* __restrict__ csr, int* __restrict__ rowptr,
                      int* __restrict__ rowend, float* __restrict__ norm) {
    __shared__ int cnt[128];
    __shared__ int sm[128];              // inclusive prefix over 128 bins
    __shared__ int cur[128];
    __shared__ unsigned short stage[CAP];   // 9 KB
    int b = blockIdx.x, tid = threadIdx.x;
    if (tid < 128) cnt[tid] = 0;
    __syncthreads();
    int beg = b * CAP;
    int m = cursor[b];                      // edge count in this bucket
    for (int j = tid; j < m; j += 1024)
        atomicAdd(&cnt[(packed[beg + j] >> 16) & 127], 1);
    __syncthreads();
    if (tid < 64) {                      // wave 0: 2 bins/lane inclusive scan
        int a = cnt[2 * tid], c1 = cnt[2 * tid + 1];
        int s = a + c1;
        for (int off = 1; off < 64; off <<= 1) {
            int t = __shfl_up(s, off, 64);
            if (tid >= off) s += t;
        }
        sm[2 * tid + 1] = s;             // incl(2t+1)
        sm[2 * tid] = s - c1;            // incl(2t)
    }
    __syncthreads();
    if (tid < 128) {
        int incl = sm[tid];
        int excl = incl - cnt[tid];
        int node = b * 128 + tid;
        if (node < N) {
            rowptr[node] = beg + excl;
            rowend[node] = beg + incl;
            norm[node] = cnt[tid] ? rsqrtf((float)cnt[tid]) : 0.0f;
        }
        cur[tid] = excl;                 // local offset within stage
    }
    __syncthreads();
    for (int j = tid; j < m; j += 1024) {
        unsigned p = packed[beg + j];
        int slot = atomicAdd(&cur[(p >> 16) & 127], 1);
        stage[slot] = (unsigned short)(p & 0xFFFFu);
    }
    __syncthreads();
    unsigned* du = (unsigned*)(csr + beg);  // beg even, base 4B-aligned
    const unsigned* su = (const unsigned*)stage;
    int mu = m >> 1;
    for (int k = tid; k < mu; k += 1024) du[k] = su[k];
    if ((m & 1) && tid == 0) csr[beg + m - 1] = stage[m - 1];
}

// K3: h2[row][d] = (sum_k x[row][k] * W[k][d]) * norm[row], stored fp16.
// Grid-stride over 16-row tiles: W staged to LDS once per block (256 blocks)
// instead of once per tile (3125).
__global__ void k_gemm(const float* __restrict__ x, const float* __restrict__ W,
                       const float* __restrict__ norm, __half* __restrict__ h2) {
    __shared__ float Wl[64 * 64];
    __shared__ float xs[16][64];
    int tid = threadIdx.x;
    ((float4*)Wl)[tid] = ((const float4*)W)[tid];   // 1024 float4 = full W
    int r = tid >> 6, d = tid & 63;
    for (int tile = blockIdx.x; tile < N / 16; tile += 256) {   // 3125 tiles
        int row = tile * 16 + r;
        __syncthreads();                  // xs reuse + (first iter) Wl ready
        xs[r][d] = x[row * 64 + d];
        __syncthreads();
        float a = 0.0f;
#pragma unroll
        for (int k = 0; k < 64; ++k) a = fmaf(xs[r][k], Wl[k * 64 + d], a);
        h2[row * 64 + d] = __float2half(a * norm[row]);
    }
}

// K4: fused aggregate + dst-norm + bias + softplus.
// One wave per node; edge indices captured up-front (u16/lane, deg<=64);
// gather loop gets src via __shfl — no memory dependency on the index leg.
// Unroll x8 pairs = 16 edges / 8 gathers in flight per iteration for MLP.
// All __shfl calls run with the full wave active; only accumulates diverge.
__global__ void k_aggregate(const int* __restrict__ rowptr, const int* __restrict__ rowend,
                            const unsigned short* __restrict__ csr,
                            const __half* __restrict__ h2, const float* __restrict__ norm,
                            const float* __restrict__ bias, float* __restrict__ out) {
    int node = blockIdx.x * 4 + (threadIdx.x >> 6);
    int lane = threadIdx.x & 63;
    int half = lane >> 5;          // which edge of the pair
    int fl = lane & 31;            // feature-pair index (features 2fl, 2fl+1)
    const __half2* h2v = (const __half2*)h2;   // row stride 32
    int beg = rowptr[node];
    int end = rowend[node];
    int deg = end - beg;
    int myidx = (beg + lane < end) ? (int)csr[beg + lane] : 0;
    int window = deg < 64 ? deg : 64;   // wave-uniform
    int npair = window >> 1;
    float ax = 0.0f, ay = 0.0f, bx = 0.0f, by = 0.0f;
    int p = 0;
    for (; p + 7 < npair; p += 8) {          // 16 edges, 8 gathers in flight
        int s0 = __shfl(myidx, 2 * p + half, 64);
        int s1 = __shfl(myidx, 2 * p + 2 + half, 64);
        int s2 = __shfl(myidx, 2 * p + 4 + half, 64);
        int s3 = __shfl(myidx, 2 * p + 6 + half, 64);
        int s4 = __shfl(myidx, 2 * p + 8 + half, 64);
        int s5 = __shfl(myidx, 2 * p + 10 + half, 64);
        int s6 = __shfl(myidx, 2 * p + 12 + half, 64);
        int s7 = __shfl(myidx, 2 * p + 14 + half, 64);
        float2 v0 = __half22float2(h2v[s0 * 32 + fl]);
        float2 v1 = __half22float2(h2v[s1 * 32 + fl]);
        float2 v2 = __half22float2(h2v[s2 * 32 + fl]);
        float2 v3 = __half22float2(h2v[s3 * 32 + fl]);
        float2 v4 = __half22float2(h2v[s4 * 32 + fl]);
        float2 v5 = __half22float2(h2v[s5 * 32 + fl]);
        float2 v6 = __half22float2(h2v[s6 * 32 + fl]);
        float2 v7 = __half22float2(h2v[s7 * 32 + fl]);
        ax += v0.x + v2.x + v4.x + v6.x;  ay += v0.y + v2.y + v4.y + v6.y;
        bx += v1.x + v3.x + v5.x + v7.x;  by += v1.y + v3.y + v5.y + v7.y;
    }
    for (; p < npair; ++p) {                 // pair tail (uniform trip count)
        int s = __shfl(myidx, 2 * p + half, 64);
        float2 v = __half22float2(h2v[s * 32 + fl]);
        ax += v.x;  ay += v.y;
    }
    if (window & 1) {                        // wave-uniform: all lanes shfl
        int s = __shfl(myidx, window - 1, 64);
        float2 v = __half22float2(h2v[s * 32 + fl]);
        if (half == 0) { ax += v.x;  ay += v.y; }
    }
    if (deg > 64) {                          // rare fallback, direct loads
        int j = beg + 64;
        for (; j + 1 < end; j += 2) {
            int s = csr[j + half];
            float2 v = __half22float2(h2v[s * 32 + fl]);
            ax += v.x;  ay += v.y;
        }
        if (j < end) {
            int s = csr[j];
            float2 v = __half22float2(h2v[s * 32 + fl]);
            if (half == 0) { ax += v.x;  ay += v.y; }
        }
    }
    ax += bx;  ay += by;
    ax += __shfl_xor(ax, 32, 64);            // combine the two half-waves
    ay += __shfl_xor(ay, 32, 64);
    if (half == 0) {
        float nrm = norm[node];
        float2 bs = ((const float2*)bias)[fl];
        float vx = ax * nrm + bs.x;
        float vy = ay * nrm + bs.y;
        float2 o;
        o.x = fmaxf(vx, 0.0f) + log1pf(expf(-fabsf(vx)));
        o.y = fmaxf(vy, 0.0f) + log1pf(expf(-fabsf(vy)));
        ((float2*)out)[node * 32 + fl] = o;
    }
}

extern "C" void kernel_launch(void* const* d_in, const int* in_sizes, int n_in,
                              void* d_out, int out_size, void* d_ws, size_t ws_size,
                              hipStream_t stream) {
    // inputs: t(f32,1), x(f32,N*D), weight(f32,D*D), bias(f32,D), src(i32,E), dst(i32,E)
    const float* x    = (const float*)d_in[1];
    const float* W    = (const float*)d_in[2];
    const float* bias = (const float*)d_in[3];
    const int* src = (const int*)d_in[4];
    const int* dst = (const int*)d_in[5];
    float* out = (float*)d_out;

    // workspace layout (~17.9 MB; poisoned 0xAA every call — every buffer is
    // fully written before it is read)
    char* ws = (char*)d_ws;
    __half*         h2     = (__half*)(ws);                     // 6.4 MB
    unsigned*       packed = (unsigned*)(ws + 6400000);         // NBUCK*CAP*4 = 7.21 MB
    unsigned short* csr    = (unsigned short*)(ws + 13606912);  // NBUCK*CAP*2 = 3.6 MB
    int*            rowptr = (int*)(ws + 17210368);             // N*4
    int*            rowend = (int*)(ws + 17410368);             // N*4
    float*          norm   = (float*)(ws + 17610368);           // N*4
    int*            cursor = (int*)(ws + 17810368);             // NBUCK*4 (counts)

    hipMemsetAsync(cursor, 0, NBUCK * sizeof(int), stream);
    k_bucket   <<<BBLOCKS, BTHREADS, 0, stream>>>(src, dst, cursor, packed);
    k_csr      <<<NBUCK, 1024, 0, stream>>>(cursor, packed, csr, rowptr, rowend, norm);
    k_gemm     <<<256, 1024, 0, stream>>>(x, W, norm, h2);
    k_aggregate<<<(N + 3) / 4, 256, 0, stream>>>(rowptr, rowend, csr, h2, norm, bias, out);
}

// Round 18
// 161.349 us; speedup vs baseline: 1.0348x; 1.0348x over previous
//
#include <hip/hip_runtime.h>
#include <hip/hip_fp16.h>

constexpr int N = 50000;        // nodes
constexpr int D = 64;           // feature dim
constexpr int E = 1600000;      // edges
constexpr int NBUCK = (N + 127) / 128;   // 391 buckets of 128 nodes (dst>>7)
constexpr int CAP = 4608;                // bucket window capacity (mean 4092)
constexpr int BTHREADS = 512;
constexpr int BBLOCKS = 512;             // 2 blocks/CU exactly
constexpr int EPB = E / BBLOCKS;         // 3125 edges per block (exact)
constexpr int CPT = (EPB + BTHREADS - 1) / BTHREADS;  // 7

// ---------------------------------------------------------------------------
// K0: init per-bucket window cursors (cursor[b] = b*CAP)
__global__ void k_init(int* __restrict__ cursor) {
    int t = threadIdx.x;
    if (t < NBUCK) cursor[t] = t * CAP;
}

// K1: privatized counting-sort scatter -> fixed-capacity bucket windows.
// packed = dst<<16 | src (both < 65536); bucket = packed>>23.
// Edges permuted into bucket-sorted order in LDS first (contiguous chunk
// writes). Scan = hierarchical wave shfl. Grid = 512 blocks = 2/CU balanced.
__global__ void k_bucket(const int* __restrict__ src, const int* __restrict__ dst,
                         int* __restrict__ cursor, unsigned* __restrict__ packed) {
    __shared__ int lh[NBUCK];
    __shared__ int scanI[NBUCK];         // inclusive prefix over buckets
    __shared__ int wsum[8];
    __shared__ int lb[NBUCK];
    __shared__ unsigned stage[EPB];      // 12.5 KB
    int tid = threadIdx.x;
    if (tid < NBUCK) lh[tid] = 0;
    __syncthreads();
    int base_e = blockIdx.x * EPB;
    unsigned pk[CPT];
    int bn[CPT], rk[CPT];
#pragma unroll
    for (int i = 0; i < CPT; ++i) {
        int idx = i * BTHREADS + tid;
        if (idx < EPB) {
            int e = base_e + idx;
            int d = dst[e];
            int s = src[e];
            bn[i] = d >> 7;
            pk[i] = ((unsigned)d << 16) | (unsigned)s;
            rk[i] = atomicAdd(&lh[bn[i]], 1);
        } else bn[i] = -1;
    }
    __syncthreads();
    // hierarchical inclusive scan of lh[0..NBUCK) into scanI
    int w = tid >> 6, l = tid & 63;
    int v = (tid < NBUCK) ? lh[tid] : 0;
    for (int off = 1; off < 64; off <<= 1) {
        int t = __shfl_up(v, off, 64);
        if (l >= off) v += t;
    }
    if (tid < NBUCK) scanI[tid] = v;
    if (l == 63) wsum[w] = v;
    __syncthreads();
    if (tid < 64) {                      // wave 0 scans the 8 wave sums
        int s = (tid < 8) ? wsum[tid] : 0;
        for (int off = 1; off < 8; off <<= 1) {
            int t = __shfl_up(s, off, 64);
            if (tid >= off) s += t;
        }
        if (tid < 8) wsum[tid] = s;
    }
    __syncthreads();
    if (tid < NBUCK && w > 0) scanI[tid] += wsum[w - 1];
    if (tid < NBUCK) {
        int c = lh[tid];
        lb[tid] = c ? atomicAdd(&cursor[tid], c) : 0;   // one global atomic/bucket/block
    }
    __syncthreads();
#pragma unroll
    for (int i = 0; i < CPT; ++i) {
        if (bn[i] >= 0) {
            int eb = (bn[i] == 0) ? 0 : scanI[bn[i] - 1];
            stage[eb + rk[i]] = pk[i];   // LDS scatter into bucket-sorted order
        }
    }
    __syncthreads();
    for (int j = tid; j < EPB; j += BTHREADS) {
        unsigned vv = stage[j];
        int bk = vv >> 23;               // dst>>7
        int eb = (bk == 0) ? 0 : scanI[bk - 1];
        packed[lb[bk] + (j - eb)] = vv;  // contiguous within each chunk
    }
}

// K2: one block (1024 thr) per 128-node bucket — LDS hist + single-wave shfl
// scan -> rowptr/rowend/norm; fill node-sorted u16 src into LDS stage, then
// coalesced uint copy-out to the bucket's CSR window.
__global__ void k_csr(const int* __restrict__ cursor, const unsigned* __restrict__ packed,
                      unsigned short* __restrict__ csr, int* __restrict__ rowptr,
                      int* __restrict__ rowend, float* __restrict__ norm) {
    __shared__ int cnt[128];
    __shared__ int sm[128];              // inclusive prefix over 128 bins
    __shared__ int cur[128];
    __shared__ unsigned short stage[CAP];   // 9 KB
    int b = blockIdx.x, tid = threadIdx.x;
    if (tid < 128) cnt[tid] = 0;
    __syncthreads();
    int beg = b * CAP;
    int m = cursor[b] - beg;                // edges in this bucket
    for (int j = tid; j < m; j += 1024)
        atomicAdd(&cnt[(packed[beg + j] >> 16) & 127], 1);
    __syncthreads();
    if (tid < 64) {                      // wave 0: 2 bins/lane inclusive scan
        int a = cnt[2 * tid], c1 = cnt[2 * tid + 1];
        int s = a + c1;
        for (int off = 1; off < 64; off <<= 1) {
            int t = __shfl_up(s, off, 64);
            if (tid >= off) s += t;
        }
        sm[2 * tid + 1] = s;             // incl(2t+1)
        sm[2 * tid] = s - c1;            // incl(2t)
    }
    __syncthreads();
    if (tid < 128) {
        int incl = sm[tid];
        int excl = incl - cnt[tid];
        int node = b * 128 + tid;
        if (node < N) {
            rowptr[node] = beg + excl;
            rowend[node] = beg + incl;
            norm[node] = cnt[tid] ? rsqrtf((float)cnt[tid]) : 0.0f;
        }
        cur[tid] = excl;                 // local offset within stage
    }
    __syncthreads();
    for (int j = tid; j < m; j += 1024) {
        unsigned p = packed[beg + j];
        int slot = atomicAdd(&cur[(p >> 16) & 127], 1);
        stage[slot] = (unsigned short)(p & 0xFFFFu);
    }
    __syncthreads();
    unsigned* du = (unsigned*)(csr + beg);  // beg even, base 4B-aligned
    const unsigned* su = (const unsigned*)stage;
    int mu = m >> 1;
    for (int k = tid; k < mu; k += 1024) du[k] = su[k];
    if ((m & 1) && tid == 0) csr[beg + m - 1] = stage[m - 1];
}

// K3: h2[row][d] = (sum_k x[row][k] * W[k][d]) * norm[row], stored fp16
__global__ void k_gemm(const float* __restrict__ x, const float* __restrict__ W,
                       const float* __restrict__ norm, __half* __restrict__ h2) {
    __shared__ float Wl[64 * 64];
    __shared__ float xs[16][64];
    int tid = threadIdx.x;
    const float4* W4 = (const float4*)W;
    float4* Wl4 = (float4*)Wl;
    Wl4[tid] = W4[tid];
    int r = tid >> 6, d = tid & 63;
    int row = blockIdx.x * 16 + r;
    xs[r][d] = x[row * 64 + d];
    __syncthreads();
    float a = 0.0f;
#pragma unroll
    for (int k = 0; k < 64; ++k) a = fmaf(xs[r][k], Wl[k * 64 + d], a);
    h2[row * 64 + d] = __float2half(a * norm[row]);
}

// K4: fused aggregate + dst-norm + bias + softplus.
// One wave per node; edge indices captured up-front (u16/lane, deg<=64);
// gather loop gets src via __shfl — no memory dependency on the index leg.
// All __shfl calls run with the full wave active; only accumulates diverge.
__global__ void k_aggregate(const int* __restrict__ rowptr, const int* __restrict__ rowend,
                            const unsigned short* __restrict__ csr,
                            const __half* __restrict__ h2, const float* __restrict__ norm,
                            const float* __restrict__ bias, float* __restrict__ out) {
    int node = blockIdx.x * 4 + (threadIdx.x >> 6);
    int lane = threadIdx.x & 63;
    int half = lane >> 5;          // which edge of the pair
    int fl = lane & 31;            // feature-pair index (features 2fl, 2fl+1)
    const __half2* h2v = (const __half2*)h2;   // row stride 32
    int beg = rowptr[node];
    int end = rowend[node];
    int deg = end - beg;
    int myidx = (beg + lane < end) ? (int)csr[beg + lane] : 0;
    int window = deg < 64 ? deg : 64;   // wave-uniform
    int npair = window >> 1;
    float ax = 0.0f, ay = 0.0f, bx = 0.0f, by = 0.0f;
    int p = 0;
    for (; p + 3 < npair; p += 4) {          // 8 edges per iteration, no index loads
        int s0 = __shfl(myidx, 2 * p + half, 64);
        int s1 = __shfl(myidx, 2 * p + 2 + half, 64);
        int s2 = __shfl(myidx, 2 * p + 4 + half, 64);
        int s3 = __shfl(myidx, 2 * p + 6 + half, 64);
        float2 v0 = __half22float2(h2v[s0 * 32 + fl]);
        float2 v1 = __half22float2(h2v[s1 * 32 + fl]);
        float2 v2 = __half22float2(h2v[s2 * 32 + fl]);
        float2 v3 = __half22float2(h2v[s3 * 32 + fl]);
        ax += v0.x + v2.x;  ay += v0.y + v2.y;
        bx += v1.x + v3.x;  by += v1.y + v3.y;
    }
    for (; p < npair; ++p) {                 // pair tail (uniform trip count)
        int s = __shfl(myidx, 2 * p + half, 64);
        float2 v = __half22float2(h2v[s * 32 + fl]);
        ax += v.x;  ay += v.y;
    }
    if (window & 1) {                        // wave-uniform: all lanes shfl
        int s = __shfl(myidx, window - 1, 64);
        float2 v = __half22float2(h2v[s * 32 + fl]);
        if (half == 0) { ax += v.x;  ay += v.y; }
    }
    if (deg > 64) {                          // rare fallback, direct loads
        int j = beg + 64;
        for (; j + 1 < end; j += 2) {
            int s = csr[j + half];
            float2 v = __half22float2(h2v[s * 32 + fl]);
            ax += v.x;  ay += v.y;
        }
        if (j < end) {
            int s = csr[j];
            float2 v = __half22float2(h2v[s * 32 + fl]);
            if (half == 0) { ax += v.x;  ay += v.y; }
        }
    }
    ax += bx;  ay += by;
    ax += __shfl_xor(ax, 32, 64);            // combine the two half-waves
    ay += __shfl_xor(ay, 32, 64);
    if (half == 0) {
        float nrm = norm[node];
        float2 bs = ((const float2*)bias)[fl];
        float vx = ax * nrm + bs.x;
        float vy = ay * nrm + bs.y;
        float2 o;
        o.x = fmaxf(vx, 0.0f) + log1pf(expf(-fabsf(vx)));
        o.y = fmaxf(vy, 0.0f) + log1pf(expf(-fabsf(vy)));
        ((float2*)out)[node * 32 + fl] = o;
    }
}

extern "C" void kernel_launch(void* const* d_in, const int* in_sizes, int n_in,
                              void* d_out, int out_size, void* d_ws, size_t ws_size,
                              hipStream_t stream) {
    // inputs: t(f32,1), x(f32,N*D), weight(f32,D*D), bias(f32,D), src(i32,E), dst(i32,E)
    const float* x    = (const float*)d_in[1];
    const float* W    = (const float*)d_in[2];
    const float* bias = (const float*)d_in[3];
    const int* src = (const int*)d_in[4];
    const int* dst = (const int*)d_in[5];
    float* out = (float*)d_out;

    // workspace layout (~17.9 MB; poisoned 0xAA every call — every buffer is
    // fully written before it is read)
    char* ws = (char*)d_ws;
    __half*         h2     = (__half*)(ws);                     // 6.4 MB
    unsigned*       packed = (unsigned*)(ws + 6400000);         // NBUCK*CAP*4 = 7.21 MB
    unsigned short* csr    = (unsigned short*)(ws + 13606912);  // NBUCK*CAP*2 = 3.6 MB
    int*            rowptr = (int*)(ws + 17210368);             // N*4
    int*            rowend = (int*)(ws + 17410368);             // N*4
    float*          norm   = (float*)(ws + 17610368);           // N*4
    int*            cursor = (int*)(ws + 17810368);             // NBUCK*4

    k_init     <<<1, 512, 0, stream>>>(cursor);
    k_bucket   <<<BBLOCKS, BTHREADS, 0, stream>>>(src, dst, cursor, packed);
    k_csr      <<<NBUCK, 1024, 0, stream>>>(cursor, packed, csr, rowptr, rowend, norm);
    k_gemm     <<<(N + 15) / 16, 1024, 0, stream>>>(x, W, norm, h2);
    k_aggregate<<<(N + 3) / 4, 256, 0, stream>>>(rowptr, rowend, csr, h2, norm, bias, out);
}